// Round 19
// baseline (308.413 us; speedup 1.0000x reference)
//
#include <hip/hip_runtime.h>
#include <hip/hip_bf16.h>

#define C_CLS   1000
#define U_PX    10
#define D_DIM   512
#define B_BATCH 4096
#define P_PX    (C_CLS * U_PX)     // 10000
#define ALPHA_F 32.0f
#define DELTA_F 0.1f

#define BM 256
#define BN 80        // 8 complete classes per tile; 10000/80 = 125
#define BK 64        // 128 B per LDS row, linear (global_load_lds dest)
#define SIMP 84      // padded per-wave sim row in f32
#define NBLK ((B_BATCH / BM) * (P_PX / BN))   // 2000 GEMM blocks

// LDS: A [256][128B] @0 (32K) + B [80][128B] @32768 (10K) = 43008 B, single buffer.
// After the K-loop, bytes 0..21503 are reused as 4 per-wave sim chunks [16][84] f32.
#define A_OFF   0
#define B_OFF   32768
#define SMEM_SZ 43008

// ws accumulator region: pos_sum[10000] | neg_sum[10000] | accum[2 dbl | cnt | done]
#define ZERO_DBL (2 * P_PX + 4)    // 20004 doubles zeroed at start of every call

typedef __attribute__((ext_vector_type(8))) short bf16x8;
typedef __attribute__((ext_vector_type(4))) float f32x4;

typedef __attribute__((address_space(1))) const void gv_t;
typedef __attribute__((address_space(3))) void lv_t;

__device__ __forceinline__ void gload_lds16(const void* g, void* lds) {
    __builtin_amdgcn_global_load_lds((gv_t*)g, (lv_t*)lds, 16, 0, 0);
}

__device__ __forceinline__ unsigned int f2bf(float f) {
    union { float f; unsigned u; } c; c.f = f;
    unsigned u = c.u;
    return (u + 0x7FFF + ((u >> 16) & 1)) >> 16;   // RN-even
}

// ---------- row L2-normalize f32 -> bf16 (one wave per row) + zero accumulators ----------
__global__ __launch_bounds__(256) void norm_rows_kernel(const float* __restrict__ feat,
                                                        const float* __restrict__ prox,
                                                        unsigned int* __restrict__ xout,
                                                        unsigned int* __restrict__ pout,
                                                        double* __restrict__ zbase) {
    // first 79 blocks also zero the loss-accumulator region (pos/neg/accum/done);
    // stream order guarantees this completes before the GEMM dispatch reads it
    const int zidx = blockIdx.x * 256 + threadIdx.x;
    if (zidx < ZERO_DBL) zbase[zidx] = 0.0;

    const int wid  = threadIdx.x >> 6;
    const int lane = threadIdx.x & 63;
    int row = blockIdx.x * 4 + wid;
    const float* in;
    unsigned int* out;
    if (row < B_BATCH) { in = feat + (size_t)row * D_DIM;   out = xout + (size_t)row * (D_DIM / 2); }
    else { row -= B_BATCH; in = prox + (size_t)row * D_DIM; out = pout + (size_t)row * (D_DIM / 2); }
    const float4 v0 = reinterpret_cast<const float4*>(in)[lane * 2];
    const float4 v1 = reinterpret_cast<const float4*>(in)[lane * 2 + 1];
    float ss = v0.x*v0.x + v0.y*v0.y + v0.z*v0.z + v0.w*v0.w
             + v1.x*v1.x + v1.y*v1.y + v1.z*v1.z + v1.w*v1.w;
    #pragma unroll
    for (int off = 1; off < 64; off <<= 1) ss += __shfl_xor(ss, off, 64);
    const float inv = 1.0f / fmaxf(sqrtf(ss), 1e-12f);
    uint4 o;
    o.x = f2bf(v0.x * inv) | (f2bf(v0.y * inv) << 16);
    o.y = f2bf(v0.z * inv) | (f2bf(v0.w * inv) << 16);
    o.z = f2bf(v1.x * inv) | (f2bf(v1.y * inv) << 16);
    o.w = f2bf(v1.z * inv) | (f2bf(v1.w * inv) << 16);
    *reinterpret_cast<uint4*>(out + lane * 4) = o;
}

// ---------- fused GEMM + logits + loss partials + last-block finalize ----------
__global__ __launch_bounds__(256, 3) void fused_gemm_kernel(
    const unsigned short* __restrict__ xbf,   // [B][D] normalized bf16
    const unsigned short* __restrict__ pbf,   // [P][D] normalized bf16
    const int*            __restrict__ labels,
    float*                __restrict__ logits,  // [B][C]
    double*               __restrict__ pos_sum, // [P]
    double*               __restrict__ neg_sum, // [P]
    double*               __restrict__ accum,   // [0]=posAcc [1]=negAcc [2].lo=cnt [3].lo=done
    float*                __restrict__ out_loss)
{
    __shared__ __align__(16) char smem[SMEM_SZ];
    __shared__ int lab_lds[BM];
    __shared__ unsigned lastFlag;

    const int t    = threadIdx.x;
    // Natural grid order (R5/R7-proven L2 locality): x = m-tile (fastest), y = n-tile.
    const int m0   = blockIdx.x * BM;
    const int n0   = blockIdx.y * BN;
    const int wid  = t >> 6;
    const int lane = t & 63;
    const int l15  = lane & 15;
    const int kgrp = lane >> 4;          // 0..3

    if (t < BM) lab_lds[t] = labels[m0 + t];

    // source pre-swizzle for linear global_load_lds dest (rule #21):
    // within each 1KiB chunk (8 rows of 128B), lane l writes LDS (row=l>>3, c16=l&7)
    // and must fetch global chunk (l&7) ^ (l>>3)
    const int srow = lane >> 3;                  // 0..7 within chunk
    const int scol = (lane & 7) ^ srow;          // swizzled 16B-chunk index

    // read-side swizzled K-offsets, loop-invariant: ((kk8*4+kgrp) ^ (l15&7)) << 4
    const int koff0 = ((kgrp    ) ^ (l15 & 7)) << 4;
    const int koff1 = ((kgrp + 4) ^ (l15 & 7)) << 4;

    f32x4 acc[4][5];
    #pragma unroll
    for (int m = 0; m < 4; ++m)
        #pragma unroll
        for (int n = 0; n < 5; ++n) acc[m][n] = (f32x4){0.f, 0.f, 0.f, 0.f};

    for (int ks = 0; ks < D_DIM / BK; ++ks) {
        const int kbase = ks * BK;
        // ---- stage: A 32 chunks (8 iters/wave), B 10 chunks ----
        #pragma unroll
        for (int c = wid; c < 32; c += 4)
            gload_lds16(xbf + (size_t)(m0 + c * 8 + srow) * D_DIM + kbase + scol * 8,
                        smem + A_OFF + c * 1024);
        for (int c = wid; c < 10; c += 4)
            gload_lds16(pbf + (size_t)(n0 + c * 8 + srow) * D_DIM + kbase + scol * 8,
                        smem + B_OFF + c * 1024);
        __syncthreads();   // drains vmcnt(0): tile staged
        // ---- compute: 40 MFMA / wave ----
        __builtin_amdgcn_s_setprio(1);
        #pragma unroll
        for (int kk8 = 0; kk8 < 2; ++kk8) {
            const int koff = kk8 ? koff1 : koff0;
            bf16x8 b[5];
            #pragma unroll
            for (int n = 0; n < 5; ++n)
                b[n] = *reinterpret_cast<const bf16x8*>(smem + B_OFF + (n * 16 + l15) * 128 + koff);
            #pragma unroll
            for (int m = 0; m < 4; ++m) {
                const bf16x8 a = *reinterpret_cast<const bf16x8*>(
                    smem + A_OFF + (wid * 64 + m * 16 + l15) * 128 + koff);
                #pragma unroll
                for (int n = 0; n < 5; ++n)
                    acc[m][n] = __builtin_amdgcn_mfma_f32_16x16x32_bf16(a, b[n], acc[m][n], 0, 0, 0);
            }
        }
        __builtin_amdgcn_s_setprio(0);
        __syncthreads();   // all reads done before next stage overwrites
    }

    // ---- loss partials fully in-register ----
    // lane holds sim(row = wid*64 + m*16 + kgrp*4 + r, col = n*16 + l15) in acc[m][n][r]
    {
        int labv[16];
        #pragma unroll
        for (int m = 0; m < 4; ++m)
            #pragma unroll
            for (int r = 0; r < 4; ++r)
                labv[m * 4 + r] = lab_lds[wid * 64 + m * 16 + kgrp * 4 + r];
        #pragma unroll
        for (int n = 0; n < 5; ++n) {
            const int col = n * 16 + l15;
            const int cls = (n0 + col) / U_PX;
            float pos = 0.f, neg = 0.f;
            #pragma unroll
            for (int m = 0; m < 4; ++m)
                #pragma unroll
                for (int r = 0; r < 4; ++r) {
                    const float s = acc[m][n][r];
                    const bool isp = (labv[m * 4 + r] == cls);
                    const float e = __expf(isp ? (-ALPHA_F * (s - DELTA_F))
                                               : ( ALPHA_F * (s + DELTA_F)));
                    if (isp) pos += e; else neg += e;
                }
            // reduce across the 4 kgrp lanes holding the same column (xor 16, 32)
            pos += __shfl_xor(pos, 16, 64); pos += __shfl_xor(pos, 32, 64);
            neg += __shfl_xor(neg, 16, 64); neg += __shfl_xor(neg, 32, 64);
            if (lane < 16) {
                atomicAdd(&neg_sum[n0 + col], (double)neg);
                if (pos != 0.f) atomicAdd(&pos_sum[n0 + col], (double)pos);
            }
        }
    }

    // ---- logits per wave (rows are wave-private; K-loop's final barrier passed) ----
    float* simw = reinterpret_cast<float*>(smem) + wid * (16 * SIMP);
    #pragma unroll
    for (int m = 0; m < 4; ++m) {
        #pragma unroll
        for (int n = 0; n < 5; ++n)
            #pragma unroll
            for (int r = 0; r < 4; ++r)
                simw[(kgrp * 4 + r) * SIMP + n * 16 + l15] = acc[m][n][r];
        // same-wave LDS ops: compiler inserts lgkmcnt before dependent reads
        #pragma unroll
        for (int it = 0; it < 2; ++it) {
            const int j   = lane + it * 64;       // 0..127
            const int r   = j >> 3;               // row within 16
            const int c   = j & 7;                // class within 8
            const float* s = simw + r * SIMP + c * U_PX;
            float wsum = 0.f, wssum = 0.f;
            #pragma unroll
            for (int u = 0; u < U_PX; ++u) {
                const float sv = s[u];
                const float e = __expf(sv);       // |s|<=1: no max-shift needed
                wsum += e; wssum += e * sv;
            }
            logits[(size_t)(m0 + wid * 64 + m * 16 + r) * C_CLS + (n0 / U_PX + c)] = wssum / wsum;
        }
        __builtin_amdgcn_s_waitcnt(0);            // reads drained before overwriting simw
    }

    // ---- last-finishing block runs the finalize reduction (proven counter pattern) ----
    __syncthreads();        // all waves' loss atomics issued & logits done
    __threadfence();        // device-scope visibility before signaling completion
    if (t == 0)
        lastFlag = (atomicAdd((unsigned*)(accum + 3), 1u) == NBLK - 1);
    __syncthreads();        // broadcast lastFlag (block-uniform from here)
    if (lastFlag) {
        // all 2000 blocks have fenced + signaled: pos/neg sums are final.
        // read via device-scope RMW (cross-XCD-safe, same as the old finalize kernel).
        double pAcc = 0.0, nAcc = 0.0; int cnt = 0;
        for (int p = t; p < P_PX; p += 256) {
            const double nsv = atomicAdd(&neg_sum[p], 0.0);
            nAcc += log1p(nsv);
            const double psv = atomicAdd(&pos_sum[p], 0.0);
            if (psv != 0.0) { pAcc += log1p(psv); cnt++; }   // exp-sums > 0 <=> has_pos
        }
        #pragma unroll
        for (int off = 1; off < 64; off <<= 1) {
            pAcc += __shfl_xor(pAcc, off, 64);
            nAcc += __shfl_xor(nAcc, off, 64);
            cnt  += __shfl_xor(cnt,  off, 64);
        }
        double* sred = reinterpret_cast<double*>(smem);     // reuse LDS (sim done)
        int*    cred = reinterpret_cast<int*>(smem + 64);
        if (lane == 0) { sred[wid] = pAcc; sred[4 + wid] = nAcc; cred[wid] = cnt; }
        __syncthreads();
        if (t == 0) {
            const double a0 = sred[0] + sred[1] + sred[2] + sred[3];
            const double a1 = sred[4] + sred[5] + sred[6] + sred[7];
            const int  csum = cred[0] + cred[1] + cred[2] + cred[3];
            out_loss[0] = (float)(a0 / (double)max(csum, 1) + a1 / (double)P_PX);
        }
    }
}

extern "C" void kernel_launch(void* const* d_in, const int* in_sizes, int n_in,
                              void* d_out, int out_size, void* d_ws, size_t ws_size,
                              hipStream_t stream) {
    const float* features = (const float*)d_in[0];
    const int*   labels   = (const int*)d_in[1];
    const float* proxies  = (const float*)d_in[2];
    float* out = (float*)d_out;              // [B*C] logits, then [1] loss

    char* ws = (char*)d_ws;
    unsigned short* xbf = (unsigned short*)ws;                                 // 4 MiB
    unsigned short* pbf = (unsigned short*)(ws + (size_t)B_BATCH * D_DIM * 2); // 10 MiB
    double* pos_sum = (double*)(ws + (size_t)(B_BATCH + P_PX) * D_DIM * 2);
    double* neg_sum = pos_sum + P_PX;
    double* accum   = neg_sum + P_PX;        // [2 dbl | int cnt | uint done]

    // no memset: norm_rows_kernel zeroes pos/neg/accum/done at the start of every call
    norm_rows_kernel<<<(B_BATCH + P_PX) / 4, 256, 0, stream>>>(
        features, proxies, (unsigned int*)xbf, (unsigned int*)pbf, pos_sum);

    fused_gemm_kernel<<<dim3(B_BATCH / BM, P_PX / BN), 256, 0, stream>>>(
        xbf, pbf, labels, out, pos_sum, neg_sum, accum,
        out + (size_t)B_BATCH * C_CLS);
}

// Round 20
// 86.968 us; speedup vs baseline: 3.5463x; 3.5463x over previous
//
#include <hip/hip_runtime.h>
#include <hip/hip_bf16.h>

#define C_CLS   1000
#define U_PX    10
#define D_DIM   512
#define B_BATCH 4096
#define P_PX    (C_CLS * U_PX)     // 10000
#define ALPHA_F 32.0f
#define DELTA_F 0.1f

#define BM 256
#define BN 80        // 8 complete classes per tile; 10000/80 = 125
#define BK 64        // 128 B per LDS row, linear (global_load_lds dest)
#define SIMP 84      // padded per-wave sim row in f32

// LDS: A [256][128B] @0 (32K) + B [80][128B] @32768 (10K) = 43008 B, single buffer.
// After the K-loop, bytes 0..21503 are reused as 4 per-wave sim chunks [16][84] f32.
#define A_OFF   0
#define B_OFF   32768
#define SMEM_SZ 43008

// ws accumulator region: pos_sum[10000] | neg_sum[10000] | accum[2 dbl | cnt | done]
#define ZERO_DBL (2 * P_PX + 4)    // 20004 doubles zeroed at start of every call
#define FIN_BLK  ((P_PX + 255) / 256)   // 40

typedef __attribute__((ext_vector_type(8))) short bf16x8;
typedef __attribute__((ext_vector_type(4))) float f32x4;

typedef __attribute__((address_space(1))) const void gv_t;
typedef __attribute__((address_space(3))) void lv_t;

__device__ __forceinline__ void gload_lds16(const void* g, void* lds) {
    __builtin_amdgcn_global_load_lds((gv_t*)g, (lv_t*)lds, 16, 0, 0);
}

__device__ __forceinline__ unsigned int f2bf(float f) {
    union { float f; unsigned u; } c; c.f = f;
    unsigned u = c.u;
    return (u + 0x7FFF + ((u >> 16) & 1)) >> 16;   // RN-even
}

// ---------- row L2-normalize f32 -> bf16 (one wave per row) + zero accumulators ----------
__global__ __launch_bounds__(256) void norm_rows_kernel(const float* __restrict__ feat,
                                                        const float* __restrict__ prox,
                                                        unsigned int* __restrict__ xout,
                                                        unsigned int* __restrict__ pout,
                                                        double* __restrict__ zbase) {
    // first 79 blocks also zero the loss-accumulator region (pos/neg/accum/done);
    // stream order guarantees this completes before the GEMM dispatch reads it
    const int zidx = blockIdx.x * 256 + threadIdx.x;
    if (zidx < ZERO_DBL) zbase[zidx] = 0.0;

    const int wid  = threadIdx.x >> 6;
    const int lane = threadIdx.x & 63;
    int row = blockIdx.x * 4 + wid;
    const float* in;
    unsigned int* out;
    if (row < B_BATCH) { in = feat + (size_t)row * D_DIM;   out = xout + (size_t)row * (D_DIM / 2); }
    else { row -= B_BATCH; in = prox + (size_t)row * D_DIM; out = pout + (size_t)row * (D_DIM / 2); }
    const float4 v0 = reinterpret_cast<const float4*>(in)[lane * 2];
    const float4 v1 = reinterpret_cast<const float4*>(in)[lane * 2 + 1];
    float ss = v0.x*v0.x + v0.y*v0.y + v0.z*v0.z + v0.w*v0.w
             + v1.x*v1.x + v1.y*v1.y + v1.z*v1.z + v1.w*v1.w;
    #pragma unroll
    for (int off = 1; off < 64; off <<= 1) ss += __shfl_xor(ss, off, 64);
    const float inv = 1.0f / fmaxf(sqrtf(ss), 1e-12f);
    uint4 o;
    o.x = f2bf(v0.x * inv) | (f2bf(v0.y * inv) << 16);
    o.y = f2bf(v0.z * inv) | (f2bf(v0.w * inv) << 16);
    o.z = f2bf(v1.x * inv) | (f2bf(v1.y * inv) << 16);
    o.w = f2bf(v1.z * inv) | (f2bf(v1.w * inv) << 16);
    *reinterpret_cast<uint4*>(out + lane * 4) = o;
}

// ---------- fused GEMM + logits + loss partials (4 waves, 64x80 per wave) ----------
__global__ __launch_bounds__(256, 3) void fused_gemm_kernel(
    const unsigned short* __restrict__ xbf,   // [B][D] normalized bf16
    const unsigned short* __restrict__ pbf,   // [P][D] normalized bf16
    const int*            __restrict__ labels,
    float*                __restrict__ logits,  // [B][C]
    double*               __restrict__ pos_sum, // [P]
    double*               __restrict__ neg_sum) // [P]
{
    __shared__ __align__(16) char smem[SMEM_SZ];
    __shared__ int lab_lds[BM];

    const int t    = threadIdx.x;
    // Natural grid order (R5/R7-proven L2 locality): x = m-tile (fastest), y = n-tile.
    const int m0   = blockIdx.x * BM;
    const int n0   = blockIdx.y * BN;
    const int wid  = t >> 6;
    const int lane = t & 63;
    const int l15  = lane & 15;
    const int kgrp = lane >> 4;          // 0..3

    if (t < BM) lab_lds[t] = labels[m0 + t];

    // source pre-swizzle for linear global_load_lds dest (rule #21):
    // within each 1KiB chunk (8 rows of 128B), lane l writes LDS (row=l>>3, c16=l&7)
    // and must fetch global chunk (l&7) ^ (l>>3)
    const int srow = lane >> 3;                  // 0..7 within chunk
    const int scol = (lane & 7) ^ srow;          // swizzled 16B-chunk index

    // read-side swizzled K-offsets, loop-invariant: ((kk8*4+kgrp) ^ (l15&7)) << 4
    const int koff0 = ((kgrp    ) ^ (l15 & 7)) << 4;
    const int koff1 = ((kgrp + 4) ^ (l15 & 7)) << 4;

    f32x4 acc[4][5];
    #pragma unroll
    for (int m = 0; m < 4; ++m)
        #pragma unroll
        for (int n = 0; n < 5; ++n) acc[m][n] = (f32x4){0.f, 0.f, 0.f, 0.f};

    for (int ks = 0; ks < D_DIM / BK; ++ks) {
        const int kbase = ks * BK;
        // ---- stage: A 32 chunks (8 iters/wave), B 10 chunks ----
        #pragma unroll
        for (int c = wid; c < 32; c += 4)
            gload_lds16(xbf + (size_t)(m0 + c * 8 + srow) * D_DIM + kbase + scol * 8,
                        smem + A_OFF + c * 1024);
        for (int c = wid; c < 10; c += 4)
            gload_lds16(pbf + (size_t)(n0 + c * 8 + srow) * D_DIM + kbase + scol * 8,
                        smem + B_OFF + c * 1024);
        __syncthreads();   // drains vmcnt(0): tile staged
        // ---- compute: 40 MFMA / wave ----
        __builtin_amdgcn_s_setprio(1);
        #pragma unroll
        for (int kk8 = 0; kk8 < 2; ++kk8) {
            const int koff = kk8 ? koff1 : koff0;
            bf16x8 b[5];
            #pragma unroll
            for (int n = 0; n < 5; ++n)
                b[n] = *reinterpret_cast<const bf16x8*>(smem + B_OFF + (n * 16 + l15) * 128 + koff);
            #pragma unroll
            for (int m = 0; m < 4; ++m) {
                const bf16x8 a = *reinterpret_cast<const bf16x8*>(
                    smem + A_OFF + (wid * 64 + m * 16 + l15) * 128 + koff);
                #pragma unroll
                for (int n = 0; n < 5; ++n)
                    acc[m][n] = __builtin_amdgcn_mfma_f32_16x16x32_bf16(a, b[n], acc[m][n], 0, 0, 0);
            }
        }
        __builtin_amdgcn_s_setprio(0);
        __syncthreads();   // all reads done before next stage overwrites
    }

    // ---- loss partials fully in-register ----
    // lane holds sim(row = wid*64 + m*16 + kgrp*4 + r, col = n*16 + l15) in acc[m][n][r]
    {
        int labv[16];
        #pragma unroll
        for (int m = 0; m < 4; ++m)
            #pragma unroll
            for (int r = 0; r < 4; ++r)
                labv[m * 4 + r] = lab_lds[wid * 64 + m * 16 + kgrp * 4 + r];
        #pragma unroll
        for (int n = 0; n < 5; ++n) {
            const int col = n * 16 + l15;
            const int cls = (n0 + col) / U_PX;
            float pos = 0.f, neg = 0.f;
            #pragma unroll
            for (int m = 0; m < 4; ++m)
                #pragma unroll
                for (int r = 0; r < 4; ++r) {
                    const float s = acc[m][n][r];
                    const bool isp = (labv[m * 4 + r] == cls);
                    const float e = __expf(isp ? (-ALPHA_F * (s - DELTA_F))
                                               : ( ALPHA_F * (s + DELTA_F)));
                    if (isp) pos += e; else neg += e;
                }
            // reduce across the 4 kgrp lanes holding the same column (xor 16, 32)
            pos += __shfl_xor(pos, 16, 64); pos += __shfl_xor(pos, 32, 64);
            neg += __shfl_xor(neg, 16, 64); neg += __shfl_xor(neg, 32, 64);
            if (lane < 16) {
                atomicAdd(&neg_sum[n0 + col], (double)neg);
                if (pos != 0.f) atomicAdd(&pos_sum[n0 + col], (double)pos);
            }
        }
    }

    // ---- logits per wave (rows are wave-private; K-loop's final barrier passed) ----
    float* simw = reinterpret_cast<float*>(smem) + wid * (16 * SIMP);
    #pragma unroll
    for (int m = 0; m < 4; ++m) {
        #pragma unroll
        for (int n = 0; n < 5; ++n)
            #pragma unroll
            for (int r = 0; r < 4; ++r)
                simw[(kgrp * 4 + r) * SIMP + n * 16 + l15] = acc[m][n][r];
        // same-wave LDS ops: compiler inserts lgkmcnt before dependent reads
        #pragma unroll
        for (int it = 0; it < 2; ++it) {
            const int j   = lane + it * 64;       // 0..127
            const int r   = j >> 3;               // row within 16
            const int c   = j & 7;                // class within 8
            const float* s = simw + r * SIMP + c * U_PX;
            float wsum = 0.f, wssum = 0.f;
            #pragma unroll
            for (int u = 0; u < U_PX; ++u) {
                const float sv = s[u];
                const float e = __expf(sv);       // |s|<=1: no max-shift needed
                wsum += e; wssum += e * sv;
            }
            logits[(size_t)(m0 + wid * 64 + m * 16 + r) * C_CLS + (n0 / U_PX + c)] = wssum / wsum;
        }
        __builtin_amdgcn_s_waitcnt(0);            // reads drained before overwriting simw
    }
}

// ---------- finalize: 40 blocks, parallel log1p; last block writes the scalar ----------
__global__ __launch_bounds__(256) void finalize_kernel(
    const double* __restrict__ pos_sum,
    const double* __restrict__ neg_sum,
    double*       __restrict__ accum,    // [0]=posAcc [1]=negAcc [2].lo32=cnt [3].lo32=done
    float*        __restrict__ out_loss)
{
    const int p = blockIdx.x * 256 + threadIdx.x;
    double pv = 0.0, nv = 0.0;
    int c = 0;
    if (p < P_PX) {
        nv = log1p(neg_sum[p]);
        const double ps = pos_sum[p];
        if (ps != 0.0) { pv = log1p(ps); c = 1; }   // exp-sums strictly positive => has_pos
    }
    #pragma unroll
    for (int off = 1; off < 64; off <<= 1) {
        pv += __shfl_xor(pv, off, 64);
        nv += __shfl_xor(nv, off, 64);
        c  += __shfl_xor(c,  off, 64);
    }
    if ((threadIdx.x & 63) == 0) {
        atomicAdd(&accum[0], pv);
        atomicAdd(&accum[1], nv);
        atomicAdd((int*)(accum + 2), c);
    }
    __syncthreads();        // all 4 waves' atomics issued & drained
    __threadfence();        // device-scope visibility before signaling completion
    if (threadIdx.x == 0) {
        const unsigned prev = atomicAdd((unsigned*)(accum + 3), 1u);
        if (prev == FIN_BLK - 1) {
            // last finishing block: read via device-scope RMW (cross-XCD-safe)
            const double a0 = atomicAdd(&accum[0], 0.0);
            const double a1 = atomicAdd(&accum[1], 0.0);
            const int   cnt = atomicAdd((int*)(accum + 2), 0);
            out_loss[0] = (float)(a0 / (double)max(cnt, 1) + a1 / (double)P_PX);
        }
    }
}

extern "C" void kernel_launch(void* const* d_in, const int* in_sizes, int n_in,
                              void* d_out, int out_size, void* d_ws, size_t ws_size,
                              hipStream_t stream) {
    const float* features = (const float*)d_in[0];
    const int*   labels   = (const int*)d_in[1];
    const float* proxies  = (const float*)d_in[2];
    float* out = (float*)d_out;              // [B*C] logits, then [1] loss

    char* ws = (char*)d_ws;
    unsigned short* xbf = (unsigned short*)ws;                                 // 4 MiB
    unsigned short* pbf = (unsigned short*)(ws + (size_t)B_BATCH * D_DIM * 2); // 10 MiB
    double* pos_sum = (double*)(ws + (size_t)(B_BATCH + P_PX) * D_DIM * 2);
    double* neg_sum = pos_sum + P_PX;
    double* accum   = neg_sum + P_PX;        // [2 dbl | int cnt | uint done]

    // no memset: norm_rows_kernel zeroes pos/neg/accum/done at the start of every call
    norm_rows_kernel<<<(B_BATCH + P_PX) / 4, 256, 0, stream>>>(
        features, proxies, (unsigned int*)xbf, (unsigned int*)pbf, pos_sum);

    fused_gemm_kernel<<<dim3(B_BATCH / BM, P_PX / BN), 256, 0, stream>>>(
        xbf, pbf, labels, out, pos_sum, neg_sum);

    finalize_kernel<<<FIN_BLK, 256, 0, stream>>>(pos_sum, neg_sum, accum,
                                                 out + (size_t)B_BATCH * C_CLS);
}